// Round 10
// baseline (845.780 us; speedup 1.0000x reference)
//
#include <hip/hip_runtime.h>

#define SEQ    2048
#define DK     64
#define QBLK   128
#define KVBLK  64
#define NTILE  (SEQ / KVBLK)   // 32
#define PITCH  72              // K/V LDS pitch (bf16), 144B rows
#define PPITCH 72              // P LDS pitch: row holds KVBLK=64 bf16 + pad

typedef __attribute__((ext_vector_type(8))) __bf16 bf16x8;
typedef __attribute__((ext_vector_type(4))) __bf16 bf16x4;
typedef __attribute__((ext_vector_type(2))) __bf16 bf16x2;
typedef __attribute__((ext_vector_type(4))) float  f32x4;
typedef __attribute__((ext_vector_type(4))) int    i32x4;

// 16-lane reductions via DPP row_ror (pure VALU, off the LDS pipe).
template<int CTRL>
__device__ __forceinline__ float dpp_ror(float v) {
  int i = __builtin_bit_cast(int, v);
  int r = __builtin_amdgcn_update_dpp(i, i, CTRL, 0xf, 0xf, false);
  return __builtin_bit_cast(float, r);
}
__device__ __forceinline__ float grp16_max(float v) {
  v = fmaxf(v, dpp_ror<0x128>(v));
  v = fmaxf(v, dpp_ror<0x124>(v));
  v = fmaxf(v, dpp_ror<0x122>(v));
  v = fmaxf(v, dpp_ror<0x121>(v));
  return v;
}
__device__ __forceinline__ float grp16_sum(float v) {
  v += dpp_ror<0x128>(v);
  v += dpp_ror<0x124>(v);
  v += dpp_ror<0x122>(v);
  v += dpp_ror<0x121>(v);
  return v;
}

// LDS-only barrier: global loads stay in flight across it.
__device__ __forceinline__ void block_sync_lds() {
  asm volatile("s_waitcnt lgkmcnt(0)" ::: "memory");
  __builtin_amdgcn_sched_barrier(0);
  __builtin_amdgcn_s_barrier();
  __builtin_amdgcn_sched_barrier(0);
}

// ---------------------------------------------------------------------------
// Pass 1: bit-pack the int32 mask (537 MB) into 1 bit/element (16.8 MB).
// Pure streaming, no sync, grid-stride: the 537 MB is read ONCE at full
// HBM BW instead of scattered through the attention loop where it was
// latency-bound and thrashed L2 against the K/V working set (R9 analysis).
// Bit j of output u64 word w == (M[64w + j] != 0). u16 stores, little-endian
// composition into u64 is exact.
// ---------------------------------------------------------------------------
__global__ __launch_bounds__(256)
void pack_mask(const int* __restrict__ M, unsigned short* __restrict__ W,
               int nwords16) {
  int idx    = blockIdx.x * 256 + threadIdx.x;
  int stride = gridDim.x * 256;
  for (int wi = idx; wi < nwords16; wi += stride) {
    const i32x4* p = (const i32x4*)(M + (size_t)wi * 16);
    unsigned bits = 0;
    #pragma unroll
    for (int j = 0; j < 4; ++j) {
      i32x4 v = __builtin_nontemporal_load(p + j);
      unsigned nib = (v.x != 0 ? 1u : 0u) | (v.y != 0 ? 2u : 0u) |
                     (v.z != 0 ? 4u : 0u) | (v.w != 0 ? 8u : 0u);
      bits |= nib << (j * 4);
    }
    __builtin_nontemporal_store((unsigned short)bits, &W[wi]);
  }
}

// ---------------------------------------------------------------------------
// Pass 2: flash attention. QBLK=128: 4 waves x 32 q-rows (two 16-row
// m-subtiles). KV tiles of 64. Structure identical to R9 except the mask:
// one u64 word per (row, kv-tile), same-address broadcast across the
// 16-lane group; nibble (w >> (li*4))&15 gives the 4 mask bits for score
// cols nt*16+li <-> kv=li*4+nt (K staged at permuted row pi(j)=(j&15)*4+(j>>4)).
// V staged unpermuted transposed via paired bf16x2 writes. Depth-1 register
// prefetch for mask-words/K/V; LDS-only barriers keep loads in flight.
// ---------------------------------------------------------------------------
__global__ __launch_bounds__(256, 2)
void sdpa_fwd(const float* __restrict__ Q, const float* __restrict__ K,
              const float* __restrict__ V,
              const unsigned long long* __restrict__ W,
              float* __restrict__ O)
{
  __shared__ __bf16 Klds[KVBLK][PITCH];
  __shared__ __bf16 Vt[DK][PITCH];
  __shared__ __bf16 Plds[4][32][PPITCH];

  const int tid  = threadIdx.x;
  const int w    = tid >> 6;
  const int lane = tid & 63;
  const int g    = lane >> 4;
  const int li   = lane & 15;
  const int li4  = li * 4;

  // XCD-aware bijective swizzle (512 % 8 == 0)
  const int bid = blockIdx.x;
  const int blk = (bid & 7) * 64 + (bid >> 3);
  const int qb  = blk & (SEQ / QBLK - 1);   // & 15
  const int bh  = blk >> 4;                 // b*H + h

  const float* Qp = Q + (size_t)bh * SEQ * DK;
  const float* Kp = K + (size_t)bh * SEQ * DK;
  const float* Vp = V + (size_t)bh * SEQ * DK;
  const unsigned long long* Wp = W + (size_t)bh * SEQ * (SEQ / 64);
  float*       Op = O + (size_t)bh * SEQ * DK;

  const int q0 = qb * QBLK + w * 16;   // m-subtile row base: q0 + m*64

  // K staging: thread covers K row sk, cols [sd, sd+16)
  const int sk = tid >> 2;
  const int sd = (tid & 3) * 16;
  const int sj = ((sk & 3) << 4) | (sk >> 2);   // pi^{-1}(sk)
  // V staging: thread covers rows {vk, vk+1}, cols [vd, vd+8)
  const int vk = (tid & 31) * 2;
  const int vd = (tid >> 5) * 8;

  // ---- Q fragments for both m-subtiles (scale+log2e folded) ----
  bf16x8 qfrag[2][2];
  #pragma unroll
  for (int m = 0; m < 2; ++m) {
    const float qs = 0.125f * 1.44269504088896340736f;
    const float* qr = Qp + (size_t)(q0 + m * 64 + li) * DK + g * 8;
    #pragma unroll
    for (int h2 = 0; h2 < 2; ++h2) {
      f32x4 a = *(const f32x4*)(qr + h2 * 32);
      f32x4 b = *(const f32x4*)(qr + h2 * 32 + 4);
      bf16x8 f;
      #pragma unroll
      for (int e = 0; e < 4; ++e) { f[e] = (__bf16)(a[e] * qs); f[4 + e] = (__bf16)(b[e] * qs); }
      qfrag[m][h2] = f;
    }
  }

  f32x4 acc[2][4];
  #pragma unroll
  for (int m = 0; m < 2; ++m)
    #pragma unroll
    for (int c = 0; c < 4; ++c) acc[m][c] = (f32x4){0.f, 0.f, 0.f, 0.f};
  float m_r[2][4], l_r[2][4];
  #pragma unroll
  for (int m = 0; m < 2; ++m)
    #pragma unroll
    for (int r = 0; r < 4; ++r) { m_r[m][r] = -__builtin_inff(); l_r[m][r] = 0.f; }

  f32x4 kA[4], vA[4];
  unsigned long long mw[8];   // depth-1 mask-word pipeline (2 m x 4 r)

  // ---- prologue: K/V/mask tile 0 ----
  {
    const float* ks  = Kp + (size_t)sk * DK + sd;
    const float* vs0 = Vp + (size_t)vk * DK + vd;
    const float* vs1 = Vp + (size_t)(vk + 1) * DK + vd;
    #pragma unroll
    for (int i = 0; i < 4; ++i) kA[i] = *(const f32x4*)(ks + 4 * i);
    vA[0] = *(const f32x4*)vs0; vA[1] = *(const f32x4*)(vs0 + 4);
    vA[2] = *(const f32x4*)vs1; vA[3] = *(const f32x4*)(vs1 + 4);
    #pragma unroll
    for (int m = 0; m < 2; ++m)
      #pragma unroll
      for (int r = 0; r < 4; ++r)
        mw[m * 4 + r] = Wp[(size_t)(q0 + m * 64 + 4 * g + r) * (SEQ / 64)];
  }

  for (int kt = 0; kt < NTILE; ++kt) {
    block_sync_lds();   // WAR: prev tile's LDS reads complete

    // ---- stage regs -> LDS ----
    {
      bf16x8 klo, khi;
      #pragma unroll
      for (int e = 0; e < 4; ++e) {
        klo[e] = (__bf16)kA[0][e]; klo[4 + e] = (__bf16)kA[1][e];
        khi[e] = (__bf16)kA[2][e]; khi[4 + e] = (__bf16)kA[3][e];
      }
      *(bf16x8*)&Klds[sj][sd]     = klo;
      *(bf16x8*)&Klds[sj][sd + 8] = khi;
      #pragma unroll
      for (int j = 0; j < 4; ++j) {
        bf16x2 p0; p0[0] = (__bf16)vA[0][j]; p0[1] = (__bf16)vA[2][j];
        bf16x2 p1; p1[0] = (__bf16)vA[1][j]; p1[1] = (__bf16)vA[3][j];
        *(bf16x2*)&Vt[vd + j][vk]     = p0;
        *(bf16x2*)&Vt[vd + 4 + j][vk] = p1;
      }
    }

    const int tn = (kt + 1 < NTILE) ? kt + 1 : 0;   // clamped, branch-free

    // refill K/V regs for tile kt+1 (in flight across barriers/compute)
    {
      const float* ks  = Kp + (size_t)(tn * KVBLK + sk) * DK + sd;
      const float* vs0 = Vp + (size_t)(tn * KVBLK + vk) * DK + vd;
      const float* vs1 = Vp + (size_t)(tn * KVBLK + vk + 1) * DK + vd;
      #pragma unroll
      for (int i = 0; i < 4; ++i) kA[i] = *(const f32x4*)(ks + 4 * i);
      vA[0] = *(const f32x4*)vs0; vA[1] = *(const f32x4*)(vs0 + 4);
      vA[2] = *(const f32x4*)vs1; vA[3] = *(const f32x4*)(vs1 + 4);
    }

    block_sync_lds();   // staged tile visible; global loads still in flight

    // ---- per m-subtile: QK^T -> mask+softmax -> P write ----
    #pragma unroll
    for (int m = 0; m < 2; ++m) {
      f32x4 st[4];
      #pragma unroll
      for (int nt = 0; nt < 4; ++nt) {
        bf16x8 b0 = *(const bf16x8*)&Klds[nt * 16 + li][g * 8];
        bf16x8 b1 = *(const bf16x8*)&Klds[nt * 16 + li][32 + g * 8];
        f32x4 s = (f32x4){0.f, 0.f, 0.f, 0.f};
        s = __builtin_amdgcn_mfma_f32_16x16x32_bf16(qfrag[m][0], b0, s, 0, 0, 0);
        s = __builtin_amdgcn_mfma_f32_16x16x32_bf16(qfrag[m][1], b1, s, 0, 0, 0);
        st[nt] = s;
      }

      #pragma unroll
      for (int r = 0; r < 4; ++r) {
        const unsigned nib = (unsigned)(mw[m * 4 + r] >> li4) & 15u;  // consume
        mw[m * 4 + r] = Wp[(size_t)(q0 + m * 64 + 4 * g + r) * (SEQ / 64) + tn];  // refill
        float s0 = (nib & 1u) ? -1e9f : st[0][r];
        float s1 = (nib & 2u) ? -1e9f : st[1][r];
        float s2 = (nib & 4u) ? -1e9f : st[2][r];
        float s3 = (nib & 8u) ? -1e9f : st[3][r];
        float mx    = grp16_max(fmaxf(fmaxf(s0, s1), fmaxf(s2, s3)));
        float mnew  = fmaxf(m_r[m][r], mx);
        float alpha = __builtin_amdgcn_exp2f(m_r[m][r] - mnew);
        float p0 = __builtin_amdgcn_exp2f(s0 - mnew);
        float p1 = __builtin_amdgcn_exp2f(s1 - mnew);
        float p2 = __builtin_amdgcn_exp2f(s2 - mnew);
        float p3 = __builtin_amdgcn_exp2f(s3 - mnew);
        l_r[m][r] = l_r[m][r] * alpha + grp16_sum((p0 + p1) + (p2 + p3));
        m_r[m][r] = mnew;
        acc[m][0][r] *= alpha;
        acc[m][1][r] *= alpha;
        acc[m][2][r] *= alpha;
        acc[m][3][r] *= alpha;
        bf16x4 pk;
        pk[0] = (__bf16)p0; pk[1] = (__bf16)p1; pk[2] = (__bf16)p2; pk[3] = (__bf16)p3;
        *(bf16x4*)&Plds[w][m * 16 + 4 * g + r][li * 4] = pk;
      }
    }

    // wave-private P tiles: writes land before fragment reads
    asm volatile("s_waitcnt lgkmcnt(0)" ::: "memory");
    __builtin_amdgcn_sched_barrier(0);

    // ---- PV for both m-subtiles (V frags shared across m) ----
    #pragma unroll
    for (int dt = 0; dt < 4; ++dt) {
      bf16x8 v0 = *(const bf16x8*)&Vt[dt * 16 + li][g * 8];
      bf16x8 v1 = *(const bf16x8*)&Vt[dt * 16 + li][32 + g * 8];
      #pragma unroll
      for (int m = 0; m < 2; ++m) {
        bf16x8 pa0 = *(const bf16x8*)&Plds[w][m * 16 + li][g * 8];
        bf16x8 pa1 = *(const bf16x8*)&Plds[w][m * 16 + li][32 + g * 8];
        acc[m][dt] = __builtin_amdgcn_mfma_f32_16x16x32_bf16(pa0, v0, acc[m][dt], 0, 0, 0);
        acc[m][dt] = __builtin_amdgcn_mfma_f32_16x16x32_bf16(pa1, v1, acc[m][dt], 0, 0, 0);
      }
    }
  }

  // ---- epilogue (nontemporal: O is write-once) ----
  #pragma unroll
  for (int m = 0; m < 2; ++m)
    #pragma unroll
    for (int r = 0; r < 4; ++r) {
      float inv = 1.0f / l_r[m][r];
      float* orow = Op + (size_t)(q0 + m * 64 + 4 * g + r) * DK + li;
      #pragma unroll
      for (int dt = 0; dt < 4; ++dt)
        __builtin_nontemporal_store(acc[m][dt][r] * inv, &orow[dt * 16]);
    }
}

extern "C" void kernel_launch(void* const* d_in, const int* in_sizes, int n_in,
                              void* d_out, int out_size, void* d_ws, size_t ws_size,
                              hipStream_t stream) {
  const float* Q = (const float*)d_in[0];
  const float* K = (const float*)d_in[1];
  const float* V = (const float*)d_in[2];
  const int*   M = (const int*)d_in[3];
  float*       O = (float*)d_out;

  // Pass 1: bit-pack mask into workspace (16.8 MB used of d_ws).
  const int nwords16 = 2 * 16 * SEQ * (SEQ / 16);   // 8,388,608 u16 words
  pack_mask<<<2048, 256, 0, stream>>>(M, (unsigned short*)d_ws, nwords16);

  // Pass 2: attention.
  const int nblocks = 2 * 16 * (SEQ / QBLK);  // 512
  sdpa_fwd<<<nblocks, 256, 0, stream>>>(Q, K, V,
                                        (const unsigned long long*)d_ws, O);
}